// Round 1
// 120.784 us; speedup vs baseline: 1.0946x; 1.0946x over previous
//
#include <hip/hip_runtime.h>
#include <math.h>

#define NB  4
#define NLQ 256
#define NLK 512
#define NH  256

// scale folded into projections: exp2(SC*(q+k)) = exp(2*(q+k))
#define SCALE_2LOG2E 2.885390081777927f
#define LOG2E        1.4426950408889634f

// ---------------------------------------------------------------------------
// Setup: W transposes (blocks 0..31) + per-batch mask compaction (32..35).
// ---------------------------------------------------------------------------
__global__ __launch_bounds__(256) void setup_kernel(
    const float* __restrict__ Wq, const float* __restrict__ Wk,
    const int* __restrict__ mask,
    float* __restrict__ Wtq, float* __restrict__ Wtk,
    int* __restrict__ act, int* __restrict__ nact)
{
    const int blk = blockIdx.x;
    const int t   = threadIdx.x;

    if (blk < 32) {
        // ---- transpose one 64x64 tile of Wq/Wk into Wtq/Wtk ----
        __shared__ float ts[64][65];
        const int m    = blk >> 4;               // 0: Wq, 1: Wk
        const int tile = blk & 15;
        const int h0 = (tile >> 2) * 64;
        const int c0 = (tile & 3) * 64;
        const float* W  = m ? Wk  : Wq;
        float*       Wt = m ? Wtk : Wtq;
        const int lr = t >> 4, lc = t & 15;
        #pragma unroll
        for (int i = 0; i < 4; ++i) {
            const int r = lr + 16 * i;
            const float4 d = *(const float4*)(W + (size_t)(h0 + r) * NH + c0 + lc * 4);
            ts[r][lc * 4 + 0] = d.x;
            ts[r][lc * 4 + 1] = d.y;
            ts[r][lc * 4 + 2] = d.z;
            ts[r][lc * 4 + 3] = d.w;
        }
        __syncthreads();
        #pragma unroll
        for (int i = 0; i < 4; ++i) {
            const int c = lr + 16 * i;
            float4 d;
            d.x = ts[lc * 4 + 0][c];
            d.y = ts[lc * 4 + 1][c];
            d.z = ts[lc * 4 + 2][c];
            d.w = ts[lc * 4 + 3][c];
            *(float4*)(Wt + (size_t)(c0 + c) * NH + h0 + lc * 4) = d;
        }
    } else if (blk < 32 + NB) {
        // ---- mask compaction for batch b ----
        const int b = blk - 32;
        __shared__ int wcnt[8], wpre[9];
        const int lane = t & 63, wave = t >> 6;
        const int k1 = t, k2 = t + 256;
        const int m1 = mask[b * NLK + k1];
        const int m2 = mask[b * NLK + k2];
        const unsigned long long below = (1ULL << lane) - 1ULL;
        const unsigned long long bal1 = __ballot(m1 != 0);
        const unsigned long long bal2 = __ballot(m2 != 0);
        const int r1 = __popcll(bal1 & below);
        const int r2 = __popcll(bal2 & below);
        if (lane == 0) { wcnt[wave] = __popcll(bal1); wcnt[4 + wave] = __popcll(bal2); }
        __syncthreads();
        if (t == 0) {
            int s = 0;
            #pragma unroll
            for (int w = 0; w < 8; ++w) { wpre[w] = s; s += wcnt[w]; }
            wpre[8] = s;
        }
        __syncthreads();
        const int na = wpre[8];
        if (m1) act[b * NLK + wpre[wave]     + r1] = k1;
        if (m2) act[b * NLK + wpre[4 + wave] + r2] = k2;
        if (k1 >= na) act[b * NLK + k1] = 0;     // safe tail for padded reads
        if (k2 >= na) act[b * NLK + k2] = 0;
        if (t == 0) nact[b] = na;
    }
}

// ---------------------------------------------------------------------------
// Fused projections (c-split across waves, coalesced Wt loads).
// Blocks 0..255: q rows (4/block) -> qp[b][lq][h] = exp2(scaled proj).
// Blocks 256..767: compact k slots (4/block, gathered via act) ->
//   kp_ct[b][h][j] compact-TRANSPOSED = exp2(scaled proj).
// Storing E-values lets attn compute sigmoid as rcp(fma(Eq,Ek,1)) with
// NO exp2 in the O(LQ*LK*H) loop.
// ---------------------------------------------------------------------------
__global__ __launch_bounds__(256) void prep_kernel(
    const float* __restrict__ query, const float* __restrict__ key,
    const float* __restrict__ Wtq, const float* __restrict__ bq,
    const float* __restrict__ Wtk, const float* __restrict__ bk,
    const int* __restrict__ act, const int* __restrict__ nact,
    float* __restrict__ qp, float* __restrict__ kp_ct)
{
    const int blk  = blockIdx.x;
    const int t    = threadIdx.x;
    const int wave = t >> 6;
    const int lane = t & 63;

    __shared__ float  xs[4][NH];
    __shared__ float4 ps[4][4][64];
    __shared__ int    ridx[4];

    const float *Wt, *bias;
    int b = 0, j0 = 0, r0 = 0, na = 0;
    const bool isq = (blk < NB * NLQ / 4);

    if (isq) {
        r0 = blk * 4;
        ((float4*)&xs[0][0])[t] = ((const float4*)(query + (size_t)r0 * NH))[t];
        Wt = Wtq; bias = bq;
    } else {
        b  = (blk - 256) >> 7;
        j0 = ((blk - 256) & 127) * 4;
        na = nact[b];
        if (j0 >= na) return;
        if (t < 4) ridx[t] = act[b * NLK + ((j0 + t < na) ? (j0 + t) : j0)];
        __syncthreads();
        const int r = t >> 6, c4 = t & 63;
        ((float4*)xs[r])[c4] =
            ((const float4*)(key + ((size_t)b * NLK + ridx[r]) * NH))[c4];
        Wt = Wtk; bias = bk;
    }
    __syncthreads();

    float4 acc[4];
    #pragma unroll
    for (int r = 0; r < 4; ++r) acc[r] = (float4){0.f, 0.f, 0.f, 0.f};

    const int cbase = wave * 64;
    #pragma unroll 4
    for (int cc = 0; cc < 64; ++cc) {
        const int c = cbase + cc;
        const float4 w = *(const float4*)(Wt + (size_t)c * NH + lane * 4);
        #pragma unroll
        for (int r = 0; r < 4; ++r) {
            const float xv = xs[r][c];             // LDS broadcast
            acc[r].x = fmaf(xv, w.x, acc[r].x);
            acc[r].y = fmaf(xv, w.y, acc[r].y);
            acc[r].z = fmaf(xv, w.z, acc[r].z);
            acc[r].w = fmaf(xv, w.w, acc[r].w);
        }
    }
    #pragma unroll
    for (int r = 0; r < 4; ++r) ps[wave][r][lane] = acc[r];
    __syncthreads();

    // combine: thread t -> row r = wave, h-quad l = lane
    const int r = wave, l = lane;
    const float4 p0 = ps[0][r][l], p1 = ps[1][r][l];
    const float4 p2 = ps[2][r][l], p3 = ps[3][r][l];
    const float4 bb = *(const float4*)(bias + l * 4);
    float4 o;
    o.x = (p0.x + p1.x + p2.x + p3.x + bb.x) * SCALE_2LOG2E;
    o.y = (p0.y + p1.y + p2.y + p3.y + bb.y) * SCALE_2LOG2E;
    o.z = (p0.z + p1.z + p2.z + p3.z + bb.z) * SCALE_2LOG2E;
    o.w = (p0.w + p1.w + p2.w + p3.w + bb.w) * SCALE_2LOG2E;
    // E-values: exp2 hoisted out of the attn inner loop
    o.x = __builtin_amdgcn_exp2f(o.x);
    o.y = __builtin_amdgcn_exp2f(o.y);
    o.z = __builtin_amdgcn_exp2f(o.z);
    o.w = __builtin_amdgcn_exp2f(o.w);

    if (isq) {
        *(float4*)(qp + (size_t)(r0 + r) * NH + l * 4) = o;
    } else if (j0 + r < na) {
        const int j = j0 + r;
        kp_ct[((size_t)b * NH + l * 4 + 0) * NLK + j] = o.x;
        kp_ct[((size_t)b * NH + l * 4 + 1) * NLK + j] = o.y;
        kp_ct[((size_t)b * NH + l * 4 + 2) * NLK + j] = o.z;
        kp_ct[((size_t)b * NH + l * 4 + 3) * NLK + j] = o.w;
    }
}

// ---------------------------------------------------------------------------
// Fused attn. Block = 256 threads (4 waves), 2 q rows, grid = 512.
// Score loop reads Ek = kp_ct[b][h][j]: at fixed c a wave loads 512B of
// CONSECUTIVE floats (float2/lane). Eq rows + v are LDS-staged (broadcast
// reads) so the Ek stream can't thrash them out of L1.
// sigmoid term = rcp(fma(Eq, Ek, 1))  -> 1 rcp + 2 fma per (q,k,h) point.
// Thread t: h-half hh=t>>7, slot pair p=t&127 -> slots 2p,2p+1.
// h-halves combined via LDS. Overflow slots (na>256) in a guarded pass 2.
// score'(q,k) = -2*sum_h v[h]*sigma  (shift-invariant form).
// Output: j split across 4 waves, float4 value loads, LDS cross-wave reduce.
// ---------------------------------------------------------------------------
__global__ __launch_bounds__(256) void attn_kernel(
    const float* __restrict__ qp, const float* __restrict__ kp_ct,
    const float* __restrict__ value, const int* __restrict__ mask,
    const int* __restrict__ act, const int* __restrict__ nact,
    const float* __restrict__ vvec,
    float* __restrict__ out_o, float* __restrict__ out_w)
{
    __shared__ float sc0[NLK], sc1[NLK];
    __shared__ int   actl[NLK];
    __shared__ float pA[256], pB[256], pC[256], pD[256];
    __shared__ float eqs[2][NH];
    __shared__ float vvs[NH];
    __shared__ float4 pr[2][256];

    const int blk  = blockIdx.x;
    const int b    = blk >> 7;               // 128 blocks per batch
    const int q0   = (blk & 127) * 2;
    const int t    = threadIdx.x;            // 0..255
    const int lane = t & 63;
    const int wave = t >> 6;

    const int na = nact[b];
    actl[t]       = (t < na)       ? act[b * NLK + t]       : 0;
    actl[t + 256] = (t + 256 < na) ? act[b * NLK + t + 256] : 0;

    // stage Eq rows + v vector in LDS (wave-uniform broadcast reads later)
    eqs[0][t] = qp[(size_t)(b * NLQ + q0) * NH + t];
    eqs[1][t] = qp[(size_t)(b * NLQ + q0 + 1) * NH + t];
    vvs[t]    = vvec[t];

    // zero masked out_w slots for this block's 2 rows (scatter fills actives)
    float* w0row = out_w + (size_t)(b * NLQ + q0) * NLK;
    float* w1row = w0row + NLK;
    if (!mask[b * NLK + t])       { w0row[t] = 0.f;       w1row[t] = 0.f; }
    if (!mask[b * NLK + t + 256]) { w0row[t + 256] = 0.f; w1row[t + 256] = 0.f; }
    __syncthreads();                         // eqs/vvs/actl ready

    const int hh = t >> 7;                   // h-half 0/1
    const int p  = t & 127;                  // slot pair
    const int hb = hh * 128;
    const float* kb = kp_ct + ((size_t)b * NH + hb) * NLK;

    // ---- pass 1: slots 2p, 2p+1 (covers compact slots 0..255) ----
    float a00 = 0.f, a01 = 0.f, a10 = 0.f, a11 = 0.f;
    #pragma unroll 4
    for (int c = 0; c < 128; ++c) {
        const float2 kx = *(const float2*)(kb + (size_t)c * NLK + 2 * p);
        const float eqa = eqs[0][hb + c];    // LDS broadcast
        const float eqb = eqs[1][hb + c];
        const float vh  = vvs[hb + c];
        a00 = fmaf(vh, __builtin_amdgcn_rcpf(fmaf(eqa, kx.x, 1.f)), a00);
        a01 = fmaf(vh, __builtin_amdgcn_rcpf(fmaf(eqa, kx.y, 1.f)), a01);
        a10 = fmaf(vh, __builtin_amdgcn_rcpf(fmaf(eqb, kx.x, 1.f)), a10);
        a11 = fmaf(vh, __builtin_amdgcn_rcpf(fmaf(eqb, kx.y, 1.f)), a11);
    }
    pA[t] = a00; pB[t] = a01; pC[t] = a10; pD[t] = a11;
    __syncthreads();
    if (t < 128) {
        const int s = 2 * t;
        sc0[s]     = (s     < na) ? -2.f * (pA[t] + pA[t + 128]) : -INFINITY;
        sc0[s + 1] = (s + 1 < na) ? -2.f * (pB[t] + pB[t + 128]) : -INFINITY;
    } else {
        const int p2 = t - 128;
        const int s  = 2 * p2;
        sc1[s]     = (s     < na) ? -2.f * (pC[p2] + pC[p2 + 128]) : -INFINITY;
        sc1[s + 1] = (s + 1 < na) ? -2.f * (pD[p2] + pD[p2 + 128]) : -INFINITY;
    }

    // ---- pass 2: overflow slots 256..511 (block-uniform branch) ----
    if (na > 256) {
        __syncthreads();
        a00 = a01 = a10 = a11 = 0.f;
        const int s0 = 256 + 2 * p;
        if (s0 < na) {
            #pragma unroll 4
            for (int c = 0; c < 128; ++c) {
                const float2 kx = *(const float2*)(kb + (size_t)c * NLK + s0);
                const float eqa = eqs[0][hb + c];
                const float eqb = eqs[1][hb + c];
                const float vh  = vvs[hb + c];
                a00 = fmaf(vh, __builtin_amdgcn_rcpf(fmaf(eqa, kx.x, 1.f)), a00);
                a01 = fmaf(vh, __builtin_amdgcn_rcpf(fmaf(eqa, kx.y, 1.f)), a01);
                a10 = fmaf(vh, __builtin_amdgcn_rcpf(fmaf(eqb, kx.x, 1.f)), a10);
                a11 = fmaf(vh, __builtin_amdgcn_rcpf(fmaf(eqb, kx.y, 1.f)), a11);
            }
        }
        pA[t] = a00; pB[t] = a01; pC[t] = a10; pD[t] = a11;
        __syncthreads();
        if (t < 128) {
            const int s = 256 + 2 * t;
            sc0[s]     = (s     < na) ? -2.f * (pA[t] + pA[t + 128]) : -INFINITY;
            sc0[s + 1] = (s + 1 < na) ? -2.f * (pB[t] + pB[t + 128]) : -INFINITY;
        } else {
            const int p2 = t - 128;
            const int s  = 256 + 2 * p2;
            sc1[s]     = (s     < na) ? -2.f * (pC[p2] + pC[p2 + 128]) : -INFINITY;
            sc1[s + 1] = (s + 1 < na) ? -2.f * (pD[p2] + pD[p2 + 128]) : -INFINITY;
        }
    } else {
        sc0[256 + t] = -INFINITY;
        sc1[256 + t] = -INFINITY;
    }
    __syncthreads();

    // ---- softmax: wave 0 -> q row 0, wave 1 -> q row 1 (512 slots) ----
    if (wave < 2) {
        float* row = wave ? sc1 : sc0;
        float vals[8];
        float m = -INFINITY;
        #pragma unroll
        for (int j8 = 0; j8 < 8; ++j8) {
            vals[j8] = row[lane + j8 * 64];
            m = fmaxf(m, vals[j8]);
        }
        #pragma unroll
        for (int s = 32; s >= 1; s >>= 1)
            m = fmaxf(m, __shfl_xor(m, s, 64));
        float sum = 0.0f;
        #pragma unroll
        for (int j8 = 0; j8 < 8; ++j8) {
            vals[j8] = __builtin_amdgcn_exp2f((vals[j8] - m) * LOG2E);
            sum += vals[j8];
        }
        #pragma unroll
        for (int s = 32; s >= 1; s >>= 1)
            sum += __shfl_xor(sum, s, 64);
        const float inv = __builtin_amdgcn_rcpf(sum);
        float* wout = out_w + (size_t)(b * NLQ + q0 + wave) * NLK;
        #pragma unroll
        for (int j8 = 0; j8 < 8; ++j8) {
            const int jj = lane + j8 * 64;
            const float w = vals[j8] * inv;
            row[jj] = w;                      // 0 for jj >= na
            if (jj < na) wout[actl[jj]] = w;  // masked slots stay 0
        }
    }
    __syncthreads();

    // ---- output: j split across 4 waves (j ≡ wave mod 4), thread owns
    //      4 columns c4..c4+3 via one float4 value load; LDS reduce after ----
    {
        const int c4 = lane * 4;
        const float* vb = value + (size_t)b * NLK * NH + c4;
        float4 o0 = {0.f, 0.f, 0.f, 0.f}, o1 = {0.f, 0.f, 0.f, 0.f};
        #pragma unroll 4
        for (int j = wave; j < na; j += 4) {
            const float w0 = sc0[j];          // LDS broadcast
            const float w1 = sc1[j];
            const int   rj = actl[j];
            const float4 v4 = *(const float4*)(vb + (size_t)rj * NH);
            o0.x = fmaf(w0, v4.x, o0.x); o0.y = fmaf(w0, v4.y, o0.y);
            o0.z = fmaf(w0, v4.z, o0.z); o0.w = fmaf(w0, v4.w, o0.w);
            o1.x = fmaf(w1, v4.x, o1.x); o1.y = fmaf(w1, v4.y, o1.y);
            o1.z = fmaf(w1, v4.z, o1.z); o1.w = fmaf(w1, v4.w, o1.w);
        }
        pr[0][t] = o0;
        pr[1][t] = o1;
        __syncthreads();
        if (t < 128) {
            const int row = t >> 6;           // 0 or 1
            const int l   = t & 63;
            const float4 s0 = pr[row][l];
            const float4 s1 = pr[row][l + 64];
            const float4 s2 = pr[row][l + 128];
            const float4 s3 = pr[row][l + 192];
            float4 o;
            o.x = s0.x + s1.x + s2.x + s3.x;
            o.y = s0.y + s1.y + s2.y + s3.y;
            o.z = s0.z + s1.z + s2.z + s3.z;
            o.w = s0.w + s1.w + s2.w + s3.w;
            *(float4*)(out_o + (size_t)(b * NLQ + q0 + row) * NH + l * 4) = o;
        }
    }
}

// ---------------------------------------------------------------------------
extern "C" void kernel_launch(void* const* d_in, const int* in_sizes, int n_in,
                              void* d_out, int out_size, void* d_ws, size_t ws_size,
                              hipStream_t stream) {
    const float* query = (const float*)d_in[0];
    const float* key   = (const float*)d_in[1];
    const float* value = (const float*)d_in[2];
    const int*   mask  = (const int*)  d_in[3];
    const float* Wq    = (const float*)d_in[4];
    const float* bq    = (const float*)d_in[5];
    const float* Wk    = (const float*)d_in[6];
    const float* bk    = (const float*)d_in[7];
    const float* v     = (const float*)d_in[8];
    // d_in[9] (bv) drops out of softmax -> unused

    float* out_o = (float*)d_out;                     // [4,256,256]
    float* out_w = out_o + NB * NLQ * NH;             // [4,256,512]

    float* qp    = (float*)d_ws;                      // [4,256,256] Eq
    float* kp_ct = qp + NB * NLQ * NH;                // [4,256,512] Ek compact-T
    int*   act   = (int*)(kp_ct + NB * NH * NLK);     // [4,512]
    int*   nact  = act + NB * NLK;                    // [4]

    const size_t base = (size_t)(NB * NLQ * NH) + (size_t)(NB * NH * NLK)
                      + NB * NLK + NB;                // floats+ints consumed
    float* wtq;
    if (ws_size >= (base + 2 * NH * NH) * sizeof(float)) {
        wtq = (float*)d_ws + base;                    // workspace tail
    } else {
        // park W^T in the out_w tail; attn (after prep) overwrites out_w
        wtq = out_w + (size_t)NB * NLQ * NLK - 2 * NH * NH;
    }
    float* wtk = wtq + NH * NH;

    setup_kernel<<<36, 256, 0, stream>>>(Wq, Wk, mask, wtq, wtk, act, nact);
    prep_kernel<<<NB * NLQ / 4 + NB * NLK / 4, 256, 0, stream>>>(
        query, key, wtq, bq, wtk, bk, act, nact, qp, kp_ct);
    attn_kernel<<<NB * NLQ / 2, 256, 0, stream>>>(
        qp, kp_ct, value, mask, act, nact, v, out_o, out_w);
}

// Round 2
// 112.085 us; speedup vs baseline: 1.1795x; 1.0776x over previous
//
#include <hip/hip_runtime.h>
#include <math.h>

#define NB  4
#define NLQ 256
#define NLK 512
#define NH  256

// scale folded into projections: exp2(SC*(q+k)) = exp(2*(q+k))
#define SCALE_2LOG2E 2.885390081777927f
#define LOG2E        1.4426950408889634f

// ---------------------------------------------------------------------------
// Setup: W transposes (blocks 0..31) + per-batch mask compaction (32..35).
// ---------------------------------------------------------------------------
__global__ __launch_bounds__(256) void setup_kernel(
    const float* __restrict__ Wq, const float* __restrict__ Wk,
    const int* __restrict__ mask,
    float* __restrict__ Wtq, float* __restrict__ Wtk,
    int* __restrict__ act, int* __restrict__ nact)
{
    const int blk = blockIdx.x;
    const int t   = threadIdx.x;

    if (blk < 32) {
        // ---- transpose one 64x64 tile of Wq/Wk into Wtq/Wtk ----
        __shared__ float ts[64][65];
        const int m    = blk >> 4;               // 0: Wq, 1: Wk
        const int tile = blk & 15;
        const int h0 = (tile >> 2) * 64;
        const int c0 = (tile & 3) * 64;
        const float* W  = m ? Wk  : Wq;
        float*       Wt = m ? Wtk : Wtq;
        const int lr = t >> 4, lc = t & 15;
        #pragma unroll
        for (int i = 0; i < 4; ++i) {
            const int r = lr + 16 * i;
            const float4 d = *(const float4*)(W + (size_t)(h0 + r) * NH + c0 + lc * 4);
            ts[r][lc * 4 + 0] = d.x;
            ts[r][lc * 4 + 1] = d.y;
            ts[r][lc * 4 + 2] = d.z;
            ts[r][lc * 4 + 3] = d.w;
        }
        __syncthreads();
        #pragma unroll
        for (int i = 0; i < 4; ++i) {
            const int c = lr + 16 * i;
            float4 d;
            d.x = ts[lc * 4 + 0][c];
            d.y = ts[lc * 4 + 1][c];
            d.z = ts[lc * 4 + 2][c];
            d.w = ts[lc * 4 + 3][c];
            *(float4*)(Wt + (size_t)(c0 + c) * NH + h0 + lc * 4) = d;
        }
    } else if (blk < 32 + NB) {
        // ---- mask compaction for batch b ----
        const int b = blk - 32;
        __shared__ int wcnt[8], wpre[9];
        const int lane = t & 63, wave = t >> 6;
        const int k1 = t, k2 = t + 256;
        const int m1 = mask[b * NLK + k1];
        const int m2 = mask[b * NLK + k2];
        const unsigned long long below = (1ULL << lane) - 1ULL;
        const unsigned long long bal1 = __ballot(m1 != 0);
        const unsigned long long bal2 = __ballot(m2 != 0);
        const int r1 = __popcll(bal1 & below);
        const int r2 = __popcll(bal2 & below);
        if (lane == 0) { wcnt[wave] = __popcll(bal1); wcnt[4 + wave] = __popcll(bal2); }
        __syncthreads();
        if (t == 0) {
            int s = 0;
            #pragma unroll
            for (int w = 0; w < 8; ++w) { wpre[w] = s; s += wcnt[w]; }
            wpre[8] = s;
        }
        __syncthreads();
        const int na = wpre[8];
        if (m1) act[b * NLK + wpre[wave]     + r1] = k1;
        if (m2) act[b * NLK + wpre[4 + wave] + r2] = k2;
        if (k1 >= na) act[b * NLK + k1] = 0;     // safe tail for padded reads
        if (k2 >= na) act[b * NLK + k2] = 0;
        if (t == 0) nact[b] = na;
    }
}

// ---------------------------------------------------------------------------
// Fused projections (c-split across waves, coalesced Wt loads).
// Blocks 0..255: q rows (4/block) -> qp[b][lq][h] = exp2(scaled proj).
// Blocks 256..767: compact k slots (4/block, gathered via act) ->
//   kp_ct[b][h][j] compact-TRANSPOSED = exp2(scaled proj).
// ---------------------------------------------------------------------------
__global__ __launch_bounds__(256) void prep_kernel(
    const float* __restrict__ query, const float* __restrict__ key,
    const float* __restrict__ Wtq, const float* __restrict__ bq,
    const float* __restrict__ Wtk, const float* __restrict__ bk,
    const int* __restrict__ act, const int* __restrict__ nact,
    float* __restrict__ qp, float* __restrict__ kp_ct)
{
    const int blk  = blockIdx.x;
    const int t    = threadIdx.x;
    const int wave = t >> 6;
    const int lane = t & 63;

    __shared__ float  xs[4][NH];
    __shared__ float4 ps[4][4][64];
    __shared__ int    ridx[4];

    const float *Wt, *bias;
    int b = 0, j0 = 0, r0 = 0, na = 0;
    const bool isq = (blk < NB * NLQ / 4);

    if (isq) {
        r0 = blk * 4;
        ((float4*)&xs[0][0])[t] = ((const float4*)(query + (size_t)r0 * NH))[t];
        Wt = Wtq; bias = bq;
    } else {
        b  = (blk - 256) >> 7;
        j0 = ((blk - 256) & 127) * 4;
        na = nact[b];
        if (j0 >= na) return;
        if (t < 4) ridx[t] = act[b * NLK + ((j0 + t < na) ? (j0 + t) : j0)];
        __syncthreads();
        const int r = t >> 6, c4 = t & 63;
        ((float4*)xs[r])[c4] =
            ((const float4*)(key + ((size_t)b * NLK + ridx[r]) * NH))[c4];
        Wt = Wtk; bias = bk;
    }
    __syncthreads();

    float4 acc[4];
    #pragma unroll
    for (int r = 0; r < 4; ++r) acc[r] = (float4){0.f, 0.f, 0.f, 0.f};

    const int cbase = wave * 64;
    #pragma unroll 4
    for (int cc = 0; cc < 64; ++cc) {
        const int c = cbase + cc;
        const float4 w = *(const float4*)(Wt + (size_t)c * NH + lane * 4);
        #pragma unroll
        for (int r = 0; r < 4; ++r) {
            const float xv = xs[r][c];             // LDS broadcast
            acc[r].x = fmaf(xv, w.x, acc[r].x);
            acc[r].y = fmaf(xv, w.y, acc[r].y);
            acc[r].z = fmaf(xv, w.z, acc[r].z);
            acc[r].w = fmaf(xv, w.w, acc[r].w);
        }
    }
    #pragma unroll
    for (int r = 0; r < 4; ++r) ps[wave][r][lane] = acc[r];
    __syncthreads();

    // combine: thread t -> row r = wave, h-quad l = lane
    const int r = wave, l = lane;
    const float4 p0 = ps[0][r][l], p1 = ps[1][r][l];
    const float4 p2 = ps[2][r][l], p3 = ps[3][r][l];
    const float4 bb = *(const float4*)(bias + l * 4);
    float4 o;
    o.x = (p0.x + p1.x + p2.x + p3.x + bb.x) * SCALE_2LOG2E;
    o.y = (p0.y + p1.y + p2.y + p3.y + bb.y) * SCALE_2LOG2E;
    o.z = (p0.z + p1.z + p2.z + p3.z + bb.z) * SCALE_2LOG2E;
    o.w = (p0.w + p1.w + p2.w + p3.w + bb.w) * SCALE_2LOG2E;
    // E-values: exp2 hoisted out of the attn inner loop
    o.x = __builtin_amdgcn_exp2f(o.x);
    o.y = __builtin_amdgcn_exp2f(o.y);
    o.z = __builtin_amdgcn_exp2f(o.z);
    o.w = __builtin_amdgcn_exp2f(o.w);

    if (isq) {
        *(float4*)(qp + (size_t)(r0 + r) * NH + l * 4) = o;
    } else if (j0 + r < na) {
        const int j = j0 + r;
        kp_ct[((size_t)b * NH + l * 4 + 0) * NLK + j] = o.x;
        kp_ct[((size_t)b * NH + l * 4 + 1) * NLK + j] = o.y;
        kp_ct[((size_t)b * NH + l * 4 + 2) * NLK + j] = o.z;
        kp_ct[((size_t)b * NH + l * 4 + 3) * NLK + j] = o.w;
    }
}

// ---------------------------------------------------------------------------
// Fused attn. Block = 512 threads (8 waves), 2 q rows, grid = 512.
// -> 16 waves/CU (2 blocks/CU) = 4 waves/SIMD for latency hiding (was 2).
// Score pass 1: wave = h-octant (32 c each); lane owns slots 4l..4l+3 via
// ONE float4 Ek load per c; 8 accs (4 slots x 2 q rows). Octant partials
// combined via 16 KB LDS buffer (conflict-free scalar reads).
// sigmoid term = rcp(fma(Eq, Ek, 1)); score' = -2*sum_h v[h]*sigma.
// Pass 2 (slots 256+, na>256) guarded as before. Softmax: waves 0/1.
// Output: j split across 8 waves, float4 value loads, 8-way LDS reduce
// (reusing the same 16 KB buffer).
// ---------------------------------------------------------------------------
__global__ __launch_bounds__(512) void attn_kernel(
    const float* __restrict__ qp, const float* __restrict__ kp_ct,
    const float* __restrict__ value, const int* __restrict__ mask,
    const int* __restrict__ act, const int* __restrict__ nact,
    const float* __restrict__ vvec,
    float* __restrict__ out_o, float* __restrict__ out_w)
{
    __shared__ float sc0[NLK], sc1[NLK];
    __shared__ int   actl[NLK];
    __shared__ float eqs[2][NH];
    __shared__ float vvs[NH];
    __shared__ float4 buf4[1024];  // 16 KB: score partials [2][8][64] / out partials [2][512]

    const int blk  = blockIdx.x;
    const int b    = blk >> 7;               // 128 blocks per batch
    const int q0   = (blk & 127) * 2;
    const int t    = threadIdx.x;            // 0..511
    const int lane = t & 63;
    const int wave = t >> 6;                 // 0..7

    const int na = nact[b];
    actl[t] = (t < na) ? act[b * NLK + t] : 0;
    if (t < NH) {
        eqs[0][t] = qp[(size_t)(b * NLQ + q0) * NH + t];
        eqs[1][t] = qp[(size_t)(b * NLQ + q0 + 1) * NH + t];
        vvs[t]    = vvec[t];
    }

    // zero masked out_w slots for this block's 2 rows (scatter fills actives)
    float* w0row = out_w + (size_t)(b * NLQ + q0) * NLK;
    float* w1row = w0row + NLK;
    if (!mask[b * NLK + t]) { w0row[t] = 0.f; w1row[t] = 0.f; }
    __syncthreads();                         // eqs/vvs/actl ready

    const int cb = wave * 32;                // h-octant for this wave
    const float* kb  = kp_ct + ((size_t)b * NH + cb) * NLK;
    const float* eq0 = &eqs[0][cb];
    const float* eq1 = &eqs[1][cb];
    const float* vv  = &vvs[cb];

    // ---- pass 1: slots 4*lane .. 4*lane+3 (covers compact slots 0..255) ----
    float4 a0 = {0.f, 0.f, 0.f, 0.f}, a1 = {0.f, 0.f, 0.f, 0.f};
    #pragma unroll 4
    for (int c = 0; c < 32; ++c) {
        const float4 kx = *(const float4*)(kb + (size_t)c * NLK + 4 * lane);
        const float eqa = eq0[c];            // wave-uniform LDS broadcast
        const float eqb = eq1[c];
        const float vh  = vv[c];
        a0.x = fmaf(vh, __builtin_amdgcn_rcpf(fmaf(eqa, kx.x, 1.f)), a0.x);
        a0.y = fmaf(vh, __builtin_amdgcn_rcpf(fmaf(eqa, kx.y, 1.f)), a0.y);
        a0.z = fmaf(vh, __builtin_amdgcn_rcpf(fmaf(eqa, kx.z, 1.f)), a0.z);
        a0.w = fmaf(vh, __builtin_amdgcn_rcpf(fmaf(eqa, kx.w, 1.f)), a0.w);
        a1.x = fmaf(vh, __builtin_amdgcn_rcpf(fmaf(eqb, kx.x, 1.f)), a1.x);
        a1.y = fmaf(vh, __builtin_amdgcn_rcpf(fmaf(eqb, kx.y, 1.f)), a1.y);
        a1.z = fmaf(vh, __builtin_amdgcn_rcpf(fmaf(eqb, kx.z, 1.f)), a1.z);
        a1.w = fmaf(vh, __builtin_amdgcn_rcpf(fmaf(eqb, kx.w, 1.f)), a1.w);
    }
    // ps4[r][oct][lane]: float index = r*2048 + oct*256 + (4*lane+i)
    buf4[(0 * 8 + wave) * 64 + lane] = a0;
    buf4[(1 * 8 + wave) * 64 + lane] = a1;
    __syncthreads();
    {
        // combine slots 0..255: thread t -> row r = t>>8, slot s = t&255
        const int r = t >> 8, s = t & 255;
        const float* p = (const float*)buf4 + r * 2048;
        float sum = 0.f;
        #pragma unroll
        for (int o = 0; o < 8; ++o) sum += p[o * 256 + s];   // conflict-free
        (r ? sc1 : sc0)[s] = (s < na) ? -2.f * sum : -INFINITY;
    }

    // ---- pass 2: overflow slots 256..511 (block-uniform branch) ----
    if (na > 256) {
        __syncthreads();                     // combine reads done; reuse buf4
        float4 b0 = {0.f, 0.f, 0.f, 0.f}, b1 = {0.f, 0.f, 0.f, 0.f};
        const int s0 = 256 + 4 * lane;
        if (s0 < na) {
            #pragma unroll 4
            for (int c = 0; c < 32; ++c) {
                const float4 kx = *(const float4*)(kb + (size_t)c * NLK + s0);
                const float eqa = eq0[c];
                const float eqb = eq1[c];
                const float vh  = vv[c];
                b0.x = fmaf(vh, __builtin_amdgcn_rcpf(fmaf(eqa, kx.x, 1.f)), b0.x);
                b0.y = fmaf(vh, __builtin_amdgcn_rcpf(fmaf(eqa, kx.y, 1.f)), b0.y);
                b0.z = fmaf(vh, __builtin_amdgcn_rcpf(fmaf(eqa, kx.z, 1.f)), b0.z);
                b0.w = fmaf(vh, __builtin_amdgcn_rcpf(fmaf(eqa, kx.w, 1.f)), b0.w);
                b1.x = fmaf(vh, __builtin_amdgcn_rcpf(fmaf(eqb, kx.x, 1.f)), b1.x);
                b1.y = fmaf(vh, __builtin_amdgcn_rcpf(fmaf(eqb, kx.y, 1.f)), b1.y);
                b1.z = fmaf(vh, __builtin_amdgcn_rcpf(fmaf(eqb, kx.z, 1.f)), b1.z);
                b1.w = fmaf(vh, __builtin_amdgcn_rcpf(fmaf(eqb, kx.w, 1.f)), b1.w);
            }
        }
        buf4[(0 * 8 + wave) * 64 + lane] = b0;
        buf4[(1 * 8 + wave) * 64 + lane] = b1;
        __syncthreads();
        const int r = t >> 8, s = t & 255;
        const float* p = (const float*)buf4 + r * 2048;
        float sum = 0.f;
        #pragma unroll
        for (int o = 0; o < 8; ++o) sum += p[o * 256 + s];
        (r ? sc1 : sc0)[256 + s] = (256 + s < na) ? -2.f * sum : -INFINITY;
    } else {
        const int r = t >> 8, s = t & 255;
        (r ? sc1 : sc0)[256 + s] = -INFINITY;
    }
    __syncthreads();

    // ---- softmax: wave 0 -> q row 0, wave 1 -> q row 1 (512 slots) ----
    if (wave < 2) {
        float* row = wave ? sc1 : sc0;
        float vals[8];
        float m = -INFINITY;
        #pragma unroll
        for (int j8 = 0; j8 < 8; ++j8) {
            vals[j8] = row[lane + j8 * 64];
            m = fmaxf(m, vals[j8]);
        }
        #pragma unroll
        for (int s = 32; s >= 1; s >>= 1)
            m = fmaxf(m, __shfl_xor(m, s, 64));
        float sum = 0.0f;
        #pragma unroll
        for (int j8 = 0; j8 < 8; ++j8) {
            vals[j8] = __builtin_amdgcn_exp2f((vals[j8] - m) * LOG2E);
            sum += vals[j8];
        }
        #pragma unroll
        for (int s = 32; s >= 1; s >>= 1)
            sum += __shfl_xor(sum, s, 64);
        const float inv = __builtin_amdgcn_rcpf(sum);
        float* wout = out_w + (size_t)(b * NLQ + q0 + wave) * NLK;
        #pragma unroll
        for (int j8 = 0; j8 < 8; ++j8) {
            const int jj = lane + j8 * 64;
            const float w = vals[j8] * inv;
            row[jj] = w;                      // 0 for jj >= na
            if (jj < na) wout[actl[jj]] = w;  // masked slots stay 0
        }
    }
    __syncthreads();

    // ---- output: j split across 8 waves (j ≡ wave mod 8), thread owns
    //      4 columns via one float4 value load; 8-way LDS reduce after ----
    {
        const int c4 = lane * 4;
        const float* vb = value + (size_t)b * NLK * NH + c4;
        float4 o0 = {0.f, 0.f, 0.f, 0.f}, o1 = {0.f, 0.f, 0.f, 0.f};
        #pragma unroll 4
        for (int j = wave; j < na; j += 8) {
            const float w0 = sc0[j];          // wave-uniform LDS broadcast
            const float w1 = sc1[j];
            const int   rj = actl[j];
            const float4 v4 = *(const float4*)(vb + (size_t)rj * NH);
            o0.x = fmaf(w0, v4.x, o0.x); o0.y = fmaf(w0, v4.y, o0.y);
            o0.z = fmaf(w0, v4.z, o0.z); o0.w = fmaf(w0, v4.w, o0.w);
            o1.x = fmaf(w1, v4.x, o1.x); o1.y = fmaf(w1, v4.y, o1.y);
            o1.z = fmaf(w1, v4.z, o1.z); o1.w = fmaf(w1, v4.w, o1.w);
        }
        buf4[t]       = o0;                   // row 0 partials
        buf4[512 + t] = o1;                   // row 1 partials
        __syncthreads();
        if (t < 128) {
            const int row = t >> 6;           // 0 or 1
            const int l   = t & 63;
            float4 o = buf4[row * 512 + l];
            #pragma unroll
            for (int w = 1; w < 8; ++w) {
                const float4 s = buf4[row * 512 + l + 64 * w];
                o.x += s.x; o.y += s.y; o.z += s.z; o.w += s.w;
            }
            *(float4*)(out_o + (size_t)(b * NLQ + q0 + row) * NH + l * 4) = o;
        }
    }
}

// ---------------------------------------------------------------------------
extern "C" void kernel_launch(void* const* d_in, const int* in_sizes, int n_in,
                              void* d_out, int out_size, void* d_ws, size_t ws_size,
                              hipStream_t stream) {
    const float* query = (const float*)d_in[0];
    const float* key   = (const float*)d_in[1];
    const float* value = (const float*)d_in[2];
    const int*   mask  = (const int*)  d_in[3];
    const float* Wq    = (const float*)d_in[4];
    const float* bq    = (const float*)d_in[5];
    const float* Wk    = (const float*)d_in[6];
    const float* bk    = (const float*)d_in[7];
    const float* v     = (const float*)d_in[8];
    // d_in[9] (bv) drops out of softmax -> unused

    float* out_o = (float*)d_out;                     // [4,256,256]
    float* out_w = out_o + NB * NLQ * NH;             // [4,256,512]

    float* qp    = (float*)d_ws;                      // [4,256,256] Eq
    float* kp_ct = qp + NB * NLQ * NH;                // [4,256,512] Ek compact-T
    int*   act   = (int*)(kp_ct + NB * NH * NLK);     // [4,512]
    int*   nact  = act + NB * NLK;                    // [4]

    const size_t base = (size_t)(NB * NLQ * NH) + (size_t)(NB * NH * NLK)
                      + NB * NLK + NB;                // floats+ints consumed
    float* wtq;
    if (ws_size >= (base + 2 * NH * NH) * sizeof(float)) {
        wtq = (float*)d_ws + base;                    // workspace tail
    } else {
        // park W^T in the out_w tail; attn (after prep) overwrites out_w
        wtq = out_w + (size_t)NB * NLQ * NLK - 2 * NH * NH;
    }
    float* wtk = wtq + NH * NH;

    setup_kernel<<<36, 256, 0, stream>>>(Wq, Wk, mask, wtq, wtk, act, nact);
    prep_kernel<<<NB * NLQ / 4 + NB * NLK / 4, 256, 0, stream>>>(
        query, key, wtq, bq, wtk, bk, act, nact, qp, kp_ct);
    attn_kernel<<<NB * NLQ / 2, 512, 0, stream>>>(
        qp, kp_ct, value, mask, act, nact, v, out_o, out_w);
}

// Round 4
// 106.774 us; speedup vs baseline: 1.2382x; 1.0497x over previous
//
#include <hip/hip_runtime.h>
#include <math.h>

#define NB  4
#define NLQ 256
#define NLK 512
#define NH  256

// scale folded into projections: exp2(SC*(q+k)) = exp(2*(q+k))
#define SCALE_2LOG2E 2.885390081777927f
#define LOG2E        1.4426950408889634f

// ---------------------------------------------------------------------------
// Setup: W transposes (blocks 0..31) + per-batch mask compaction (32..35).
// ---------------------------------------------------------------------------
__global__ __launch_bounds__(256) void setup_kernel(
    const float* __restrict__ Wq, const float* __restrict__ Wk,
    const int* __restrict__ mask,
    float* __restrict__ Wtq, float* __restrict__ Wtk,
    int* __restrict__ act, int* __restrict__ nact)
{
    const int blk = blockIdx.x;
    const int t   = threadIdx.x;

    if (blk < 32) {
        // ---- transpose one 64x64 tile of Wq/Wk into Wtq/Wtk ----
        __shared__ float ts[64][65];
        const int m    = blk >> 4;               // 0: Wq, 1: Wk
        const int tile = blk & 15;
        const int h0 = (tile >> 2) * 64;
        const int c0 = (tile & 3) * 64;
        const float* W  = m ? Wk  : Wq;
        float*       Wt = m ? Wtk : Wtq;
        const int lr = t >> 4, lc = t & 15;
        #pragma unroll
        for (int i = 0; i < 4; ++i) {
            const int r = lr + 16 * i;
            const float4 d = *(const float4*)(W + (size_t)(h0 + r) * NH + c0 + lc * 4);
            ts[r][lc * 4 + 0] = d.x;
            ts[r][lc * 4 + 1] = d.y;
            ts[r][lc * 4 + 2] = d.z;
            ts[r][lc * 4 + 3] = d.w;
        }
        __syncthreads();
        #pragma unroll
        for (int i = 0; i < 4; ++i) {
            const int c = lr + 16 * i;
            float4 d;
            d.x = ts[lc * 4 + 0][c];
            d.y = ts[lc * 4 + 1][c];
            d.z = ts[lc * 4 + 2][c];
            d.w = ts[lc * 4 + 3][c];
            *(float4*)(Wt + (size_t)(c0 + c) * NH + h0 + lc * 4) = d;
        }
    } else if (blk < 32 + NB) {
        // ---- mask compaction for batch b ----
        const int b = blk - 32;
        __shared__ int wcnt[8], wpre[9];
        const int lane = t & 63, wave = t >> 6;
        const int k1 = t, k2 = t + 256;
        const int m1 = mask[b * NLK + k1];
        const int m2 = mask[b * NLK + k2];
        const unsigned long long below = (1ULL << lane) - 1ULL;
        const unsigned long long bal1 = __ballot(m1 != 0);
        const unsigned long long bal2 = __ballot(m2 != 0);
        const int r1 = __popcll(bal1 & below);
        const int r2 = __popcll(bal2 & below);
        if (lane == 0) { wcnt[wave] = __popcll(bal1); wcnt[4 + wave] = __popcll(bal2); }
        __syncthreads();
        if (t == 0) {
            int s = 0;
            #pragma unroll
            for (int w = 0; w < 8; ++w) { wpre[w] = s; s += wcnt[w]; }
            wpre[8] = s;
        }
        __syncthreads();
        const int na = wpre[8];
        if (m1) act[b * NLK + wpre[wave]     + r1] = k1;
        if (m2) act[b * NLK + wpre[4 + wave] + r2] = k2;
        if (k1 >= na) act[b * NLK + k1] = 0;     // safe tail for padded reads
        if (k2 >= na) act[b * NLK + k2] = 0;
        if (t == 0) nact[b] = na;
    }
}

// ---------------------------------------------------------------------------
// Fused projections (c-split across waves, coalesced Wt loads).
// XCD batch affinity: with round-robin block->XCD dispatch, b = idx&3 pins
// each batch's kp_ct/qp production to the XCDs that attn reads them on.
// Blocks 0..255: q rows (4/block) -> qp[b][lq][h] = exp2(scaled proj).
// Blocks 256..767: compact k slots (4/block, gathered via act) ->
//   kp_ct[b][h][j] compact-TRANSPOSED = exp2(scaled proj).
// ---------------------------------------------------------------------------
__global__ __launch_bounds__(256) void prep_kernel(
    const float* __restrict__ query, const float* __restrict__ key,
    const float* __restrict__ Wtq, const float* __restrict__ bq,
    const float* __restrict__ Wtk, const float* __restrict__ bk,
    const int* __restrict__ act, const int* __restrict__ nact,
    float* __restrict__ qp, float* __restrict__ kp_ct)
{
    const int blk  = blockIdx.x;
    const int t    = threadIdx.x;
    const int wave = t >> 6;
    const int lane = t & 63;

    __shared__ float  xs[4][NH];
    __shared__ float4 ps[4][4][64];
    __shared__ int    ridx[4];

    const float *Wt, *bias;
    int b = 0, j0 = 0, r0 = 0, na = 0;
    const bool isq = (blk < NB * NLQ / 4);

    if (isq) {
        b  = blk & 3;                            // XCD affinity
        r0 = b * NLQ + (blk >> 2) * 4;           // global q-row
        ((float4*)&xs[0][0])[t] = ((const float4*)(query + (size_t)r0 * NH))[t];
        Wt = Wtq; bias = bq;
    } else {
        const int idx = blk - 256;
        b  = idx & 3;                            // XCD affinity
        j0 = (idx >> 2) * 4;
        na = nact[b];
        if (j0 >= na) return;
        if (t < 4) ridx[t] = act[b * NLK + ((j0 + t < na) ? (j0 + t) : j0)];
        __syncthreads();
        const int r = t >> 6, c4 = t & 63;
        ((float4*)xs[r])[c4] =
            ((const float4*)(key + ((size_t)b * NLK + ridx[r]) * NH))[c4];
        Wt = Wtk; bias = bk;
    }
    __syncthreads();

    float4 acc[4];
    #pragma unroll
    for (int r = 0; r < 4; ++r) acc[r] = (float4){0.f, 0.f, 0.f, 0.f};

    const int cbase = wave * 64;
    #pragma unroll 4
    for (int cc = 0; cc < 64; ++cc) {
        const int c = cbase + cc;
        const float4 w = *(const float4*)(Wt + (size_t)c * NH + lane * 4);
        #pragma unroll
        for (int r = 0; r < 4; ++r) {
            const float xv = xs[r][c];             // LDS broadcast
            acc[r].x = fmaf(xv, w.x, acc[r].x);
            acc[r].y = fmaf(xv, w.y, acc[r].y);
            acc[r].z = fmaf(xv, w.z, acc[r].z);
            acc[r].w = fmaf(xv, w.w, acc[r].w);
        }
    }
    #pragma unroll
    for (int r = 0; r < 4; ++r) ps[wave][r][lane] = acc[r];
    __syncthreads();

    // combine: thread t -> row r = wave, h-quad l = lane
    const int r = wave, l = lane;
    const float4 p0 = ps[0][r][l], p1 = ps[1][r][l];
    const float4 p2 = ps[2][r][l], p3 = ps[3][r][l];
    const float4 bb = *(const float4*)(bias + l * 4);
    float4 o;
    o.x = (p0.x + p1.x + p2.x + p3.x + bb.x) * SCALE_2LOG2E;
    o.y = (p0.y + p1.y + p2.y + p3.y + bb.y) * SCALE_2LOG2E;
    o.z = (p0.z + p1.z + p2.z + p3.z + bb.z) * SCALE_2LOG2E;
    o.w = (p0.w + p1.w + p2.w + p3.w + bb.w) * SCALE_2LOG2E;
    // E-values: exp2 hoisted out of the attn inner loop
    o.x = __builtin_amdgcn_exp2f(o.x);
    o.y = __builtin_amdgcn_exp2f(o.y);
    o.z = __builtin_amdgcn_exp2f(o.z);
    o.w = __builtin_amdgcn_exp2f(o.w);

    if (isq) {
        *(float4*)(qp + (size_t)(r0 + r) * NH + l * 4) = o;
    } else if (j0 + r < na) {
        const int j = j0 + r;
        kp_ct[((size_t)b * NH + l * 4 + 0) * NLK + j] = o.x;
        kp_ct[((size_t)b * NH + l * 4 + 1) * NLK + j] = o.y;
        kp_ct[((size_t)b * NH + l * 4 + 2) * NLK + j] = o.z;
        kp_ct[((size_t)b * NH + l * 4 + 3) * NLK + j] = o.w;
    }
}

// ---------------------------------------------------------------------------
// Fused attn. Block = 512 threads (8 waves), 2 q rows, grid = 512.
// XCD batch affinity: b = blockIdx&3 -> with round-robin dispatch, XCD x
// serves only batch x%4; per-XCD L2 working set 1.3 MB << 4 MB (no thrash).
// SINGLE score pass: wave = h-octant (32 c); lane owns slots 4l..4l+3 and,
// when na>256 (block-uniform branch), also slots 256+4l..256+4l+3 via a
// second float4 load in the SAME loop -> overflow runs parallel, not serial.
// Partials [2 rows][8 oct][512 slots] = 32 KB LDS; combine discards s>=na.
// sigmoid term = rcp(fma(Eq, Ek, 1)); score' = -2*sum_h v[h]*sigma.
// Softmax: waves 0/1. Output: j split across 8 waves, float4 value loads,
// 8-way LDS reduce (reusing the 32 KB buffer).
// ---------------------------------------------------------------------------
__global__ __launch_bounds__(512) void attn_kernel(
    const float* __restrict__ qp, const float* __restrict__ kp_ct,
    const float* __restrict__ value, const int* __restrict__ mask,
    const int* __restrict__ act, const int* __restrict__ nact,
    const float* __restrict__ vvec,
    float* __restrict__ out_o, float* __restrict__ out_w)
{
    __shared__ float sc0[NLK], sc1[NLK];
    __shared__ int   actl[NLK];
    __shared__ float eqs[2][NH];
    __shared__ float vvs[NH];
    __shared__ float4 buf4[2048];  // 32 KB: score partials [2][8][512] / out partials [2][512]

    const int blk  = blockIdx.x;
    const int b    = blk & 3;                // XCD batch affinity
    const int q0   = (blk >> 2) * 2;         // 128 q-pairs per batch
    const int t    = threadIdx.x;            // 0..511
    const int lane = t & 63;
    const int wave = t >> 6;                 // 0..7

    const int na = nact[b];
    actl[t] = (t < na) ? act[b * NLK + t] : 0;
    if (t < NH) {
        eqs[0][t] = qp[(size_t)(b * NLQ + q0) * NH + t];
        eqs[1][t] = qp[(size_t)(b * NLQ + q0 + 1) * NH + t];
        vvs[t]    = vvec[t];
    }

    // zero masked out_w slots for this block's 2 rows (scatter fills actives)
    float* w0row = out_w + (size_t)(b * NLQ + q0) * NLK;
    float* w1row = w0row + NLK;
    if (!mask[b * NLK + t]) { w0row[t] = 0.f; w1row[t] = 0.f; }
    __syncthreads();                         // eqs/vvs/actl ready

    const int cb = wave * 32;                // h-octant for this wave
    const float* kb  = kp_ct + ((size_t)b * NH + cb) * NLK;
    const float* eq0 = &eqs[0][cb];
    const float* eq1 = &eqs[1][cb];
    const float* vv  = &vvs[cb];

    // ---- single score pass ----
    float4 a0 = {0.f, 0.f, 0.f, 0.f}, a1 = {0.f, 0.f, 0.f, 0.f};  // slots 4l..
    float4 a2 = {0.f, 0.f, 0.f, 0.f}, a3 = {0.f, 0.f, 0.f, 0.f};  // slots 256+4l..
    if (na > 256) {
        #pragma unroll 4
        for (int c = 0; c < 32; ++c) {
            const float4 k1 = *(const float4*)(kb + (size_t)c * NLK + 4 * lane);
            const float4 k2 = *(const float4*)(kb + (size_t)c * NLK + 256 + 4 * lane);
            const float eqa = eq0[c];        // wave-uniform LDS broadcast
            const float eqb = eq1[c];
            const float vh  = vv[c];
            a0.x = fmaf(vh, __builtin_amdgcn_rcpf(fmaf(eqa, k1.x, 1.f)), a0.x);
            a0.y = fmaf(vh, __builtin_amdgcn_rcpf(fmaf(eqa, k1.y, 1.f)), a0.y);
            a0.z = fmaf(vh, __builtin_amdgcn_rcpf(fmaf(eqa, k1.z, 1.f)), a0.z);
            a0.w = fmaf(vh, __builtin_amdgcn_rcpf(fmaf(eqa, k1.w, 1.f)), a0.w);
            a1.x = fmaf(vh, __builtin_amdgcn_rcpf(fmaf(eqb, k1.x, 1.f)), a1.x);
            a1.y = fmaf(vh, __builtin_amdgcn_rcpf(fmaf(eqb, k1.y, 1.f)), a1.y);
            a1.z = fmaf(vh, __builtin_amdgcn_rcpf(fmaf(eqb, k1.z, 1.f)), a1.z);
            a1.w = fmaf(vh, __builtin_amdgcn_rcpf(fmaf(eqb, k1.w, 1.f)), a1.w);
            a2.x = fmaf(vh, __builtin_amdgcn_rcpf(fmaf(eqa, k2.x, 1.f)), a2.x);
            a2.y = fmaf(vh, __builtin_amdgcn_rcpf(fmaf(eqa, k2.y, 1.f)), a2.y);
            a2.z = fmaf(vh, __builtin_amdgcn_rcpf(fmaf(eqa, k2.z, 1.f)), a2.z);
            a2.w = fmaf(vh, __builtin_amdgcn_rcpf(fmaf(eqa, k2.w, 1.f)), a2.w);
            a3.x = fmaf(vh, __builtin_amdgcn_rcpf(fmaf(eqb, k2.x, 1.f)), a3.x);
            a3.y = fmaf(vh, __builtin_amdgcn_rcpf(fmaf(eqb, k2.y, 1.f)), a3.y);
            a3.z = fmaf(vh, __builtin_amdgcn_rcpf(fmaf(eqb, k2.z, 1.f)), a3.z);
            a3.w = fmaf(vh, __builtin_amdgcn_rcpf(fmaf(eqb, k2.w, 1.f)), a3.w);
        }
    } else {
        #pragma unroll 4
        for (int c = 0; c < 32; ++c) {
            const float4 k1 = *(const float4*)(kb + (size_t)c * NLK + 4 * lane);
            const float eqa = eq0[c];
            const float eqb = eq1[c];
            const float vh  = vv[c];
            a0.x = fmaf(vh, __builtin_amdgcn_rcpf(fmaf(eqa, k1.x, 1.f)), a0.x);
            a0.y = fmaf(vh, __builtin_amdgcn_rcpf(fmaf(eqa, k1.y, 1.f)), a0.y);
            a0.z = fmaf(vh, __builtin_amdgcn_rcpf(fmaf(eqa, k1.z, 1.f)), a0.z);
            a0.w = fmaf(vh, __builtin_amdgcn_rcpf(fmaf(eqa, k1.w, 1.f)), a0.w);
            a1.x = fmaf(vh, __builtin_amdgcn_rcpf(fmaf(eqb, k1.x, 1.f)), a1.x);
            a1.y = fmaf(vh, __builtin_amdgcn_rcpf(fmaf(eqb, k1.y, 1.f)), a1.y);
            a1.z = fmaf(vh, __builtin_amdgcn_rcpf(fmaf(eqb, k1.z, 1.f)), a1.z);
            a1.w = fmaf(vh, __builtin_amdgcn_rcpf(fmaf(eqb, k1.w, 1.f)), a1.w);
        }
    }
    // partials as float[2][8][512]: buf4[(r*8+w)*128 + half*64 + lane]
    buf4[(0 * 8 + wave) * 128 + lane]      = a0;
    buf4[(0 * 8 + wave) * 128 + 64 + lane] = a2;
    buf4[(1 * 8 + wave) * 128 + lane]      = a1;
    buf4[(1 * 8 + wave) * 128 + 64 + lane] = a3;
    __syncthreads();
    {
        // combine: thread t -> slot t for both rows; 8 octant adds each
        const float* pf = (const float*)buf4;
        float sA = 0.f, sB = 0.f;
        #pragma unroll
        for (int o = 0; o < 8; ++o) {
            sA += pf[o * 512 + t];           // conflict-free stride-1
            sB += pf[(8 + o) * 512 + t];
        }
        sc0[t] = (t < na) ? -2.f * sA : -INFINITY;
        sc1[t] = (t < na) ? -2.f * sB : -INFINITY;
    }
    __syncthreads();

    // ---- softmax: wave 0 -> q row 0, wave 1 -> q row 1 (512 slots) ----
    if (wave < 2) {
        float* row = wave ? sc1 : sc0;
        float vals[8];
        float m = -INFINITY;
        #pragma unroll
        for (int j8 = 0; j8 < 8; ++j8) {
            vals[j8] = row[lane + j8 * 64];
            m = fmaxf(m, vals[j8]);
        }
        #pragma unroll
        for (int s = 32; s >= 1; s >>= 1)
            m = fmaxf(m, __shfl_xor(m, s, 64));
        float sum = 0.0f;
        #pragma unroll
        for (int j8 = 0; j8 < 8; ++j8) {
            vals[j8] = __builtin_amdgcn_exp2f((vals[j8] - m) * LOG2E);
            sum += vals[j8];
        }
        #pragma unroll
        for (int s = 32; s >= 1; s >>= 1)
            sum += __shfl_xor(sum, s, 64);
        const float inv = __builtin_amdgcn_rcpf(sum);
        float* wout = out_w + (size_t)(b * NLQ + q0 + wave) * NLK;
        #pragma unroll
        for (int j8 = 0; j8 < 8; ++j8) {
            const int jj = lane + j8 * 64;
            const float w = vals[j8] * inv;
            row[jj] = w;                      // 0 for jj >= na
            if (jj < na) wout[actl[jj]] = w;  // masked slots stay 0
        }
    }
    __syncthreads();

    // ---- output: j split across 8 waves (j ≡ wave mod 8), thread owns
    //      4 columns via one float4 value load; 8-way LDS reduce after ----
    {
        const int c4 = lane * 4;
        const float* vb = value + (size_t)b * NLK * NH + c4;
        float4 o0 = {0.f, 0.f, 0.f, 0.f}, o1 = {0.f, 0.f, 0.f, 0.f};
        #pragma unroll 4
        for (int j = wave; j < na; j += 8) {
            const float w0 = sc0[j];          // wave-uniform LDS broadcast
            const float w1 = sc1[j];
            const int   rj = actl[j];
            const float4 v4 = *(const float4*)(vb + (size_t)rj * NH);
            o0.x = fmaf(w0, v4.x, o0.x); o0.y = fmaf(w0, v4.y, o0.y);
            o0.z = fmaf(w0, v4.z, o0.z); o0.w = fmaf(w0, v4.w, o0.w);
            o1.x = fmaf(w1, v4.x, o1.x); o1.y = fmaf(w1, v4.y, o1.y);
            o1.z = fmaf(w1, v4.z, o1.z); o1.w = fmaf(w1, v4.w, o1.w);
        }
        buf4[t]       = o0;                   // row 0 partials
        buf4[512 + t] = o1;                   // row 1 partials
        __syncthreads();
        if (t < 128) {
            const int row = t >> 6;           // 0 or 1
            const int l   = t & 63;
            float4 o = buf4[row * 512 + l];
            #pragma unroll
            for (int w = 1; w < 8; ++w) {
                const float4 s = buf4[row * 512 + l + 64 * w];
                o.x += s.x; o.y += s.y; o.z += s.z; o.w += s.w;
            }
            *(float4*)(out_o + (size_t)(b * NLQ + q0 + row) * NH + l * 4) = o;
        }
    }
}

// ---------------------------------------------------------------------------
extern "C" void kernel_launch(void* const* d_in, const int* in_sizes, int n_in,
                              void* d_out, int out_size, void* d_ws, size_t ws_size,
                              hipStream_t stream) {
    const float* query = (const float*)d_in[0];
    const float* key   = (const float*)d_in[1];
    const float* value = (const float*)d_in[2];
    const int*   mask  = (const int*)  d_in[3];
    const float* Wq    = (const float*)d_in[4];
    const float* bq    = (const float*)d_in[5];
    const float* Wk    = (const float*)d_in[6];
    const float* bk    = (const float*)d_in[7];
    const float* v     = (const float*)d_in[8];
    // d_in[9] (bv) drops out of softmax -> unused

    float* out_o = (float*)d_out;                     // [4,256,256]
    float* out_w = out_o + NB * NLQ * NH;             // [4,256,512]

    float* qp    = (float*)d_ws;                      // [4,256,256] Eq
    float* kp_ct = qp + NB * NLQ * NH;                // [4,256,512] Ek compact-T
    int*   act   = (int*)(kp_ct + NB * NH * NLK);     // [4,512]
    int*   nact  = act + NB * NLK;                    // [4]

    const size_t base = (size_t)(NB * NLQ * NH) + (size_t)(NB * NH * NLK)
                      + NB * NLK + NB;                // floats+ints consumed
    float* wtq;
    if (ws_size >= (base + 2 * NH * NH) * sizeof(float)) {
        wtq = (float*)d_ws + base;                    // workspace tail
    } else {
        // park W^T in the out_w tail; attn (after prep) overwrites out_w
        wtq = out_w + (size_t)NB * NLQ * NLK - 2 * NH * NH;
    }
    float* wtk = wtq + NH * NH;

    setup_kernel<<<36, 256, 0, stream>>>(Wq, Wk, mask, wtq, wtk, act, nact);
    prep_kernel<<<NB * NLQ / 4 + NB * NLK / 4, 256, 0, stream>>>(
        query, key, wtq, bq, wtk, bk, act, nact, qp, kp_ct);
    attn_kernel<<<NB * NLQ / 2, 512, 0, stream>>>(
        qp, kp_ct, value, mask, act, nact, v, out_o, out_w);
}